// Round 10
// baseline (169.189 us; speedup 1.0000x reference)
//
#include <hip/hip_runtime.h>

typedef unsigned short u16;
typedef float f32x4 __attribute__((ext_vector_type(4)));
typedef short bf16x8 __attribute__((ext_vector_type(8)));

#define MFMA16(a, b, c) __builtin_amdgcn_mfma_f32_16x16x32_bf16((a), (b), (c), 0, 0, 0)
// XOR swizzle in 16B (8-short) units within a 64-short row
#define SWZ8(row, off) ((off) ^ (((row) & 7) << 3))

#define CFENCE() asm volatile("" ::: "memory")
#define BARRIER() do { CFENCE(); __builtin_amdgcn_s_barrier(); CFENCE(); } while (0)
#define VMW(n) asm volatile("s_waitcnt vmcnt(" #n ")" ::: "memory")

// round-to-nearest-even f32 -> bf16 (software; proven rounds 0-2)
static __device__ __forceinline__ u16 f2bf(float f) {
  union { float f; unsigned u; } c; c.f = f;
  unsigned r = c.u + 0x7fffu + ((c.u >> 16) & 1u);
  return (u16)(r >> 16);
}

// hardware 2^x (v_exp_f32 IS exp2)
static __device__ __forceinline__ float exp2_hw(float x) {
  float r;
  asm("v_exp_f32 %0, %1" : "=v"(r) : "v"(x));
  return r;
}

// packed f32x2 -> bf16x2 (used ONLY for P, the tolerance-insensitive site)
static __device__ __forceinline__ unsigned cvtpk(float lo, float hi) {
  unsigned r;
  asm("v_cvt_pk_bf16_f32 %0, %1, %2" : "=v"(r) : "v"(lo), "v"(hi));
  return r;
}

static __device__ __forceinline__ void llds16(u16* l, const u16* g) {
  __builtin_amdgcn_global_load_lds((const __attribute__((address_space(1))) void*)g,
                                   (__attribute__((address_space(3))) void*)l, 16, 0, 0);
}

// ---------------- fused prep (weights transpose) + LayerNorm ----------------
__global__ __launch_bounds__(256) void prep_ln(
    const float* __restrict__ x, const float* __restrict__ g,
    const float* __restrict__ be, u16* __restrict__ xn,
    const float* __restrict__ w_qkv, const float* __restrict__ w_out,
    u16* __restrict__ wqkvT, u16* __restrict__ woutT) {
  __shared__ u16 tile[64][66];
  int bid = blockIdx.x;
  int tid = threadIdx.x;
  if (bid < 2048) {
    int row = bid * 4 + (tid >> 6);
    int lane = tid & 63;
    const float4* xr = (const float4*)(x + (size_t)row * 512) + lane * 2;
    float4 v0 = xr[0], v1 = xr[1];
    float s = v0.x + v0.y + v0.z + v0.w + v1.x + v1.y + v1.z + v1.w;
    float ss = v0.x * v0.x + v0.y * v0.y + v0.z * v0.z + v0.w * v0.w +
               v1.x * v1.x + v1.y * v1.y + v1.z * v1.z + v1.w * v1.w;
#pragma unroll
    for (int msk = 32; msk >= 1; msk >>= 1) {
      s += __shfl_xor(s, msk, 64);
      ss += __shfl_xor(ss, msk, 64);
    }
    float mu = s * (1.f / 512.f);
    float var = ss * (1.f / 512.f) - mu * mu;
    float rs = rsqrtf(var + 1e-5f);
    const float4* gp = (const float4*)g + lane * 2;
    const float4* bp = (const float4*)be + lane * 2;
    float4 g0 = gp[0], g1 = gp[1], b0 = bp[0], b1 = bp[1];
    union { u16 h[8]; uint4 q; } o;
    o.h[0] = f2bf((v0.x - mu) * rs * g0.x + b0.x);
    o.h[1] = f2bf((v0.y - mu) * rs * g0.y + b0.y);
    o.h[2] = f2bf((v0.z - mu) * rs * g0.z + b0.z);
    o.h[3] = f2bf((v0.w - mu) * rs * g0.w + b0.w);
    o.h[4] = f2bf((v1.x - mu) * rs * g1.x + b1.x);
    o.h[5] = f2bf((v1.y - mu) * rs * g1.y + b1.y);
    o.h[6] = f2bf((v1.z - mu) * rs * g1.z + b1.z);
    o.h[7] = f2bf((v1.w - mu) * rs * g1.w + b1.w);
    *(uint4*)&xn[(size_t)row * 512 + lane * 8] = o.q;
    return;
  }
  int pb = bid - 2048;
  const float* src;
  u16* dst;
  int C, tr, tc;
  if (pb < 192) {  // w_qkv [512][1536] -> wqkvT [1536][512]
    src = w_qkv; dst = wqkvT; C = 1536;
    tr = (pb & 7) * 64;
    tc = (pb >> 3) * 64;
  } else {         // w_out [512][512] -> woutT [512][512]
    int b2 = pb - 192;
    src = w_out; dst = woutT; C = 512;
    tr = (b2 & 7) * 64;
    tc = (b2 >> 3) * 64;
  }
  int i = tid >> 4;
  int j4 = (tid & 15) * 4;
#pragma unroll
  for (int p = 0; p < 4; ++p) {
    int row = i + p * 16;
    float4 v = *(const float4*)&src[(size_t)(tr + row) * C + tc + j4];
    tile[row][j4 + 0] = f2bf(v.x);
    tile[row][j4 + 1] = f2bf(v.y);
    tile[row][j4 + 2] = f2bf(v.z);
    tile[row][j4 + 3] = f2bf(v.w);
  }
  __syncthreads();
  int j = tid >> 3;
  int i8 = (tid & 7) * 8;
#pragma unroll
  for (int p = 0; p < 2; ++p) {
    int orow = j + p * 32;
    union { u16 h[8]; uint4 q; } o;
#pragma unroll
    for (int s = 0; s < 8; ++s) o.h[s] = tile[i8 + s][orow];
    *(uint4*)&dst[(size_t)(tc + orow) * 512 + tr + i8] = o.q;
  }
}

// ---------------- QKV GEMM: [8192,512] x [512,1536], scatter q/k/vT ----------------
// 128-thread blocks, 2 waves, wave tile 64x128 -> 32 MFMA per K-step per wave
// (2x the MFMA:overhead ratio of the 64x64 wave tile). BK=32 double-buffered,
// counted vmcnt(8). K order unchanged -> bit-identical results.
__global__ __launch_bounds__(128) void gemm_qkv(
    const u16* __restrict__ A, const u16* __restrict__ BT,
    u16* __restrict__ qb, u16* __restrict__ kb, u16* __restrict__ vtb) {
  __shared__ u16 ls[16384];  // per buf: A[128][32] 4096 u16 + B[128][32] 4096 u16
  int bid = blockIdx.x;
  int xcd = bid & 7, sq = bid >> 3;       // sq 0..95
  int m0 = (xcd * 8 + (sq & 7)) * 128;    // 64 m-tiles
  int n0 = (sq >> 3) * 128;               // 12 n-tiles
  int sec = n0 >> 9;                      // 0=q 1=k 2=v, uniform per block
  int tid = threadIdx.x;
  int lane = tid & 63, wave = tid >> 6;
  int wm = wave * 64;
  int lr = lane & 15, lq = lane >> 4;
  // staging geometry: 512 16B-units per operand, 128 threads -> 4 each
  int ur = tid >> 2, uc = tid & 3;
  const u16* Ab = &A[(size_t)(m0 + ur) * 512 + ((uc ^ (ur & 3)) * 8)];
  const u16* Bb = &BT[(size_t)(n0 + ur) * 512 + ((uc ^ (ur & 3)) * 8)];

#define STAGEG(bf, kt_)                                            \
  do {                                                             \
    u16* la_ = ls + (bf) * 8192;                                   \
    u16* lb_ = la_ + 4096;                                         \
    int gc = (kt_) * 32;                                           \
    _Pragma("unroll")                                              \
    for (int p = 0; p < 4; ++p) {                                  \
      llds16(&la_[(tid + 128 * p) * 8], Ab + p * 16384 + gc);      \
      llds16(&lb_[(tid + 128 * p) * 8], Bb + p * 16384 + gc);      \
    }                                                              \
  } while (0)

  f32x4 acc[4][8] = {};
  STAGEG(0, 0);
  for (int kt = 0; kt < 16; ++kt) {
    int cur = kt & 1;
    if (kt < 15) {
      STAGEG(cur ^ 1, kt + 1);
      VMW(8);
    } else {
      VMW(0);
    }
    BARRIER();
    u16* la = ls + cur * 8192;
    u16* lb = la + 4096;
    bf16x8 af[4], bfr[8];
#pragma unroll
    for (int i = 0; i < 4; ++i) {
      int ra = wm + i * 16 + lr;
      af[i] = *(const bf16x8*)&la[ra * 32 + ((lq ^ (ra & 3)) * 8)];
    }
#pragma unroll
    for (int j = 0; j < 8; ++j) {
      int rb = j * 16 + lr;
      bfr[j] = *(const bf16x8*)&lb[rb * 32 + ((lq ^ (rb & 3)) * 8)];
    }
    __builtin_amdgcn_s_setprio(1);
#pragma unroll
    for (int i = 0; i < 4; ++i)
#pragma unroll
      for (int j = 0; j < 8; ++j)
        acc[i][j] = MFMA16(af[i], bfr[j], acc[i][j]);
    __builtin_amdgcn_s_setprio(0);
    BARRIER();
  }
#undef STAGEG
  // ---- epilogue: acc -> LDS [128][128] u16 (swizzled) -> coalesced stores ----
  int b = m0 >> 11, t0 = m0 & 2047;
  float sc = (sec == 0) ? 0.180336880f : 1.0f;
  if (sec < 2) {
#pragma unroll
    for (int i = 0; i < 4; ++i)
#pragma unroll
      for (int j = 0; j < 8; ++j) {
        int col = j * 16 + lr;
#pragma unroll
        for (int r = 0; r < 4; ++r) {
          int row = wm + i * 16 + lq * 4 + r;
          ls[row * 128 + (col ^ ((row & 7) << 3))] = f2bf(acc[i][j][r] * sc);
        }
      }
    __syncthreads();
    u16* dst = (sec == 0) ? qb : kb;
#pragma unroll
    for (int s = 0; s < 16; ++s) {
      int li = s * 128 + tid;
      int row = li >> 4, c8 = (li & 15) * 8;
      uint4 v = *(uint4*)&ls[row * 128 + (c8 ^ ((row & 7) << 3))];
      int gn = n0 + c8;
      int h = (gn >> 6) & 7, d = gn & 63;
      *(uint4*)&dst[((size_t)(b * 8 + h) * 2048 + t0 + row) * 64 + d] = v;
    }
  } else {
#pragma unroll
    for (int i = 0; i < 4; ++i)
#pragma unroll
      for (int j = 0; j < 8; ++j) {
        int col = j * 16 + lr;
#pragma unroll
        for (int r = 0; r < 4; ++r) {
          int row = wm + i * 16 + lq * 4 + r;
          ls[col * 128 + (row ^ ((col & 7) << 3))] = f2bf(acc[i][j][r]);
        }
      }
    __syncthreads();
#pragma unroll
    for (int s = 0; s < 16; ++s) {
      int li = s * 128 + tid;
      int dcol = li >> 4, t8 = (li & 15) * 8;
      uint4 v = *(uint4*)&ls[dcol * 128 + (t8 ^ ((dcol & 7) << 3))];
      int gn = n0 + dcol;
      int h = (gn >> 6) & 7, d = gn & 63;
      *(uint4*)&vtb[((size_t)(b * 8 + h) * 64 + d) * 2048 + t0 + t8] = v;
    }
  }
}

// ---------------- frame-causal flash attention (R5 structure + defer-max) ----------------
__global__ __launch_bounds__(256) void attn_kernel(
    const u16* __restrict__ qb, const u16* __restrict__ kb,
    const u16* __restrict__ vtb, u16* __restrict__ ao) {
  int blk = blockIdx.x;
  int xcd = blk & 7;
  int seq = blk >> 3;            // 0..127
  int bh = xcd * 4 + (seq & 3);  // 4 bh per XCD -> L2-resident K/V
  int qf = 31 - (seq >> 2);      // heavy frames first
  int tid = threadIdx.x, lane = tid & 63, wave = tid >> 6;
  int lr = lane & 15, lq = lane >> 4;
  __shared__ u16 lsK[2][64 * 64], lsV[2][64 * 64];
  __shared__ u16 lsP[4][16 * 64];
  const u16* kfb = kb + (size_t)bh * 2048 * 64;
  const u16* vfb = vtb + (size_t)bh * 64 * 2048;

  int ci0 = tid, ci1 = 256 + tid;
  int r0 = ci0 >> 3, cb0 = ci0 & 7, sw0 = (cb0 * 8) ^ ((r0 & 7) * 8);
  int r1 = ci1 >> 3, cb1 = ci1 & 7, sw1 = (cb1 * 8) ^ ((r1 & 7) * 8);

#define STAGE(buf, kf_)                                                        \
  do {                                                                         \
    const u16* kp = kfb + (size_t)(kf_) * 64 * 64;                             \
    llds16(&lsK[buf][ci0 * 8], &kp[(size_t)r0 * 64 + sw0]);                    \
    llds16(&lsK[buf][ci1 * 8], &kp[(size_t)r1 * 64 + sw1]);                    \
    llds16(&lsV[buf][ci0 * 8], &vfb[(size_t)r0 * 2048 + (kf_) * 64 + sw0]);    \
    llds16(&lsV[buf][ci1 * 8], &vfb[(size_t)r1 * 2048 + (kf_) * 64 + sw1]);    \
  } while (0)

  STAGE(0, 0);

  const u16* qbase = qb + ((size_t)bh * 2048 + qf * 64) * 64;
  int qrow = wave * 16 + lr;
  bf16x8 qa0 = *(const bf16x8*)&qbase[qrow * 64 + lq * 8];
  bf16x8 qa1 = *(const bf16x8*)&qbase[qrow * 64 + 32 + lq * 8];

  f32x4 o[4] = {};
  float m = -1e30f, l = 0.f;
  u16* pw = lsP[wave];

  for (int kf = 0; kf <= qf; ++kf) {
    int cur = kf & 1;
    if (kf < qf) {
      STAGE(cur ^ 1, kf + 1);
      VMW(4);
    } else {
      VMW(0);
    }
    BARRIER();
    f32x4 s[4];
    __builtin_amdgcn_s_setprio(1);
#pragma unroll
    for (int c = 0; c < 4; ++c) {
      int rk = c * 16 + lr;
      bf16x8 k0 = *(const bf16x8*)&lsK[cur][rk * 64 + SWZ8(rk, lq * 8)];
      bf16x8 k1 = *(const bf16x8*)&lsK[cur][rk * 64 + SWZ8(rk, 32 + lq * 8)];
      f32x4 z = {};
      z = MFMA16(k0, qa0, z);
      z = MFMA16(k1, qa1, z);
      s[c] = z;
    }
    __builtin_amdgcn_s_setprio(0);
    float m0 = fmaxf(fmaxf(s[0][0], s[0][1]), fmaxf(s[0][2], s[0][3]));
    float m1 = fmaxf(fmaxf(s[1][0], s[1][1]), fmaxf(s[1][2], s[1][3]));
    float m2 = fmaxf(fmaxf(s[2][0], s[2][1]), fmaxf(s[2][2], s[2][3]));
    float m3 = fmaxf(fmaxf(s[3][0], s[3][1]), fmaxf(s[3][2], s[3][3]));
    float mx = fmaxf(fmaxf(m0, m1), fmaxf(m2, m3));
    mx = fmaxf(mx, __shfl_xor(mx, 16, 64));
    mx = fmaxf(mx, __shfl_xor(mx, 32, 64));
    if (!__all(mx <= m + 8.f)) {
      float mn = fmaxf(m, mx);
      float al = exp2_hw(m - mn);
      m = mn;
      l *= al;
      float al0 = __shfl(al, lq * 4 + 0, 64);
      float al1 = __shfl(al, lq * 4 + 1, 64);
      float al2 = __shfl(al, lq * 4 + 2, 64);
      float al3 = __shfl(al, lq * 4 + 3, 64);
#pragma unroll
      for (int oc = 0; oc < 4; ++oc) {
        o[oc][0] *= al0;
        o[oc][1] *= al1;
        o[oc][2] *= al2;
        o[oc][3] *= al3;
      }
    }
    float sum = 0.f;
#pragma unroll
    for (int c = 0; c < 4; ++c) {
#pragma unroll
      for (int r = 0; r < 4; ++r) {
        s[c][r] = exp2_hw(s[c][r] - m);
        sum += s[c][r];
      }
    }
    sum += __shfl_xor(sum, 16, 64);
    sum += __shfl_xor(sum, 32, 64);
    l += sum;
#pragma unroll
    for (int c = 0; c < 4; ++c) {
      union { unsigned u[2]; uint2 q2; } pk;
      pk.u[0] = cvtpk(s[c][0], s[c][1]);
      pk.u[1] = cvtpk(s[c][2], s[c][3]);
      *(uint2*)&pw[lr * 64 + ((c * 16 + lq * 4) ^ ((lr & 7) * 8))] = pk.q2;
    }
    bf16x8 pa0 = *(const bf16x8*)&pw[lr * 64 + SWZ8(lr, lq * 8)];
    bf16x8 pa1 = *(const bf16x8*)&pw[lr * 64 + SWZ8(lr, 32 + lq * 8)];
    __builtin_amdgcn_s_setprio(1);
#pragma unroll
    for (int oc = 0; oc < 4; ++oc) {
      int rv = oc * 16 + lr;
      bf16x8 v0 = *(const bf16x8*)&lsV[cur][rv * 64 + SWZ8(rv, lq * 8)];
      bf16x8 v1 = *(const bf16x8*)&lsV[cur][rv * 64 + SWZ8(rv, 32 + lq * 8)];
      o[oc] = MFMA16(pa0, v0, o[oc]);
      o[oc] = MFMA16(pa1, v1, o[oc]);
    }
    __builtin_amdgcn_s_setprio(0);
    BARRIER();
  }
#undef STAGE
  float inv = 1.0f / l;
  float i0 = __shfl(inv, lq * 4 + 0, 64);
  float i1 = __shfl(inv, lq * 4 + 1, 64);
  float i2 = __shfl(inv, lq * 4 + 2, 64);
  float i3 = __shfl(inv, lq * 4 + 3, 64);
  int b = bh >> 3, h = bh & 7;
#pragma unroll
  for (int oc = 0; oc < 4; ++oc) {
    int q = qf * 64 + wave * 16 + lq * 4;
    int col = h * 64 + oc * 16 + lr;
    ao[((size_t)b * 2048 + q + 0) * 512 + col] = f2bf(o[oc][0] * i0);
    ao[((size_t)b * 2048 + q + 1) * 512 + col] = f2bf(o[oc][1] * i1);
    ao[((size_t)b * 2048 + q + 2) * 512 + col] = f2bf(o[oc][2] * i2);
    ao[((size_t)b * 2048 + q + 3) * 512 + col] = f2bf(o[oc][3] * i3);
  }
}

// ---------------- out GEMM: [8192,512] x [512,512] + bias -> fp32 ----------------
// Same 2-wave 64x128 wave-tile structure as gemm_qkv; direct fp32 stores.
__global__ __launch_bounds__(128) void gemm_out(
    const u16* __restrict__ A, const u16* __restrict__ BT,
    const float* __restrict__ bias, float* __restrict__ out) {
  __shared__ u16 ls[16384];
  int bid = blockIdx.x;
  int xcd = bid & 7, sq = bid >> 3;     // sq 0..31
  int m0 = (xcd * 8 + (sq & 7)) * 128;  // 64 m-tiles
  int n0 = (sq >> 3) * 128;             // 4 n-tiles
  int tid = threadIdx.x;
  int lane = tid & 63, wave = tid >> 6;
  int wm = wave * 64;
  int lr = lane & 15, lq = lane >> 4;
  int ur = tid >> 2, uc = tid & 3;
  const u16* Ab = &A[(size_t)(m0 + ur) * 512 + ((uc ^ (ur & 3)) * 8)];
  const u16* Bb = &BT[(size_t)(n0 + ur) * 512 + ((uc ^ (ur & 3)) * 8)];

#define STAGEG(bf, kt_)                                            \
  do {                                                             \
    u16* la_ = ls + (bf) * 8192;                                   \
    u16* lb_ = la_ + 4096;                                         \
    int gc = (kt_) * 32;                                           \
    _Pragma("unroll")                                              \
    for (int p = 0; p < 4; ++p) {                                  \
      llds16(&la_[(tid + 128 * p) * 8], Ab + p * 16384 + gc);      \
      llds16(&lb_[(tid + 128 * p) * 8], Bb + p * 16384 + gc);      \
    }                                                              \
  } while (0)

  f32x4 acc[4][8] = {};
  STAGEG(0, 0);
  for (int kt = 0; kt < 16; ++kt) {
    int cur = kt & 1;
    if (kt < 15) {
      STAGEG(cur ^ 1, kt + 1);
      VMW(8);
    } else {
      VMW(0);
    }
    BARRIER();
    u16* la = ls + cur * 8192;
    u16* lb = la + 4096;
    bf16x8 af[4], bfr[8];
#pragma unroll
    for (int i = 0; i < 4; ++i) {
      int ra = wm + i * 16 + lr;
      af[i] = *(const bf16x8*)&la[ra * 32 + ((lq ^ (ra & 3)) * 8)];
    }
#pragma unroll
    for (int j = 0; j < 8; ++j) {
      int rb = j * 16 + lr;
      bfr[j] = *(const bf16x8*)&lb[rb * 32 + ((lq ^ (rb & 3)) * 8)];
    }
    __builtin_amdgcn_s_setprio(1);
#pragma unroll
    for (int i = 0; i < 4; ++i)
#pragma unroll
      for (int j = 0; j < 8; ++j)
        acc[i][j] = MFMA16(af[i], bfr[j], acc[i][j]);
    __builtin_amdgcn_s_setprio(0);
    BARRIER();
  }
#undef STAGEG
#pragma unroll
  for (int j = 0; j < 8; ++j) {
    int gn = n0 + j * 16 + lr;
    float bj = bias[gn];
#pragma unroll
    for (int i = 0; i < 4; ++i) {
      int gm = m0 + wm + i * 16 + lq * 4;
#pragma unroll
      for (int r = 0; r < 4; ++r)
        out[(size_t)(gm + r) * 512 + gn] = acc[i][j][r] + bj;
    }
  }
}

extern "C" void kernel_launch(void* const* d_in, const int* in_sizes, int n_in,
                              void* d_out, int out_size, void* d_ws, size_t ws_size,
                              hipStream_t stream) {
  const float* x = (const float*)d_in[0];
  const float* ln_g = (const float*)d_in[1];
  const float* ln_b = (const float*)d_in[2];
  const float* w_qkv = (const float*)d_in[3];
  const float* w_out = (const float*)d_in[4];
  const float* b_out = (const float*)d_in[5];
  float* out = (float*)d_out;
  char* ws = (char*)d_ws;

  u16* xn    = (u16*)(ws + 0);          //  8 MB  [8192][512] bf16
  u16* wqkvT = (u16*)(ws + 8388608);    //  1.5 MB [1536][512]
  u16* woutT = (u16*)(ws + 9961472);    //  0.5 MB [512][512]
  u16* qb    = (u16*)(ws + 10485760);   //  8 MB  [B,H,T,D]
  u16* kb    = (u16*)(ws + 18874368);   //  8 MB  [B,H,T,D]
  u16* vtb   = (u16*)(ws + 27262976);   //  8 MB  [B,H,D,T]
  u16* ao    = (u16*)(ws + 35651584);   //  8 MB  [8192][512]

  prep_ln<<<2304, 256, 0, stream>>>(x, ln_g, ln_b, xn, w_qkv, w_out, wqkvT, woutT);
  gemm_qkv<<<768, 128, 0, stream>>>(xn, wqkvT, qb, kb, vtb);
  attn_kernel<<<1024, 256, 0, stream>>>(qb, kb, vtb, ao);
  gemm_out<<<256, 128, 0, stream>>>(ao, woutT, b_out, out);
}